// Round 8
// baseline (231.574 us; speedup 1.0000x reference)
//
#include <hip/hip_runtime.h>

#define NB 64
#define NT 512
#define NH 1024
#define NC 8
#define NK 3
#define BT (NB*NT)             // 32768
#define LOGITS_N (NK*BT*NC)    // 786432

typedef unsigned short ushort;
typedef unsigned int uint;
typedef __attribute__((ext_vector_type(8))) short short8v;
typedef __attribute__((ext_vector_type(4))) float float4v;
union S8 { short8v v; ushort u[8]; };

// DPP controls
#define QP1  0xB1   // quad_perm [1,0,3,2] -> lane^1
#define QP2  0x4E   // quad_perm [2,3,0,1] -> lane^2
#define ROR4 0x124  // row_ror:4  -> lane^4 (value must be 8-group replicated)
#define ROR8 0x128  // row_ror:8  -> exact lane^8 within 16-row
#define HM   0x141  // row_half_mirror -> exact lane^7 within 8

template<int CTRL>
__device__ __forceinline__ float dppf(float x) {
  return __int_as_float(__builtin_amdgcn_update_dpp(0, __float_as_int(x), CTRL, 0xF, 0xF, true));
}
template<int CTRL>
__device__ __forceinline__ int dppi(int x) {
  return __builtin_amdgcn_update_dpp(0, x, CTRL, 0xF, 0xF, true);
}

__device__ __forceinline__ void gload_lds16(const void* g, void* l) {
  __builtin_amdgcn_global_load_lds(
      (const __attribute__((address_space(1))) void*)g,
      (__attribute__((address_space(3))) void*)l, 16, 0, 0);
}

// ---------- init: W -> frag-ready 3-way bf16 split WB[3][16ci][4q][64l][8] --
__global__ __launch_bounds__(256) void init_kernel(const float* __restrict__ W,
                                                   ushort* __restrict__ WB,
                                                   float* __restrict__ out) {
  const int i = blockIdx.x * 256 + threadIdx.x;   // 0..32767
  const int ci = i >> 11;
  const int rem = i & 2047;
  const int q = rem >> 9;
  const int l = (rem >> 3) & 63;
  const int e = i & 7;
  const int k = ci * 64 + (q >> 1) * 32 + ((l >> 4) << 3) + e;
  const int j = (q & 1) * 16 + (l & 15);
  float v = 0.0f;
  if (j < 24) v = W[(j >> 3) * (NC * NH) + (j & 7) * NH + k];
  const uint b = __float_as_uint(v);
  const ushort h1 = (ushort)(b >> 16);
  const float f1 = __uint_as_float(b & 0xFFFF0000u);
  const float r1 = v - f1;
  const uint b2 = __float_as_uint(r1);
  const ushort h2 = (ushort)(b2 >> 16);
  const float f2 = __uint_as_float(b2 & 0xFFFF0000u);
  const float r2 = r1 - f2;
  const ushort h3 = (ushort)(__float_as_uint(r2) >> 16);
  WB[i] = h1;
  WB[32768 + i] = h2;
  WB[65536 + i] = h3;
  if (i == 0) out[0] = 0.0f;
}

// ---------- proj v15: SEQUENTIAL row-streams, B resident in VGPRs -----------
// 256 blocks x 512 thr (8 waves), 1 block/CU. Block = 128 rows; 8 row-groups
// (rg) of 16 rows x full K=1024 = 64 KB CONTIGUOUS per stage -> each block
// streams its 512 KB strictly sequentially (fill-kernel access class; kills
// the 256B-granule DRAM page inefficiency that capped v7-v14 at ~2.3 TB/s).
// Wave w owns K-eighth [w*128,+128) forever: its 24 B-frags (3 splits x 4
// ksteps x 2 jt) live in 96 VGPRs, loaded once (B LDS/restage traffic: gone).
// Per rg: wave computes partial [16x24] (48 MFMA, 3+3 Dekker split as v12),
// 8-wave reduce via 16 KB LDS + direct store, overlapped with stage(rg+2).
// A LDS 2x64 KB dbuf; source pre-swizzled lane^(row&7), XOR'd frag read
// (2-way banks = free). Counted vmcnt(8): wait only rg's loads (T4).
__global__ __launch_bounds__(512, 2) void proj_kernel(const float* __restrict__ enc,
                                                      const ushort* __restrict__ WB,
                                                      const float* __restrict__ bias,
                                                      float* __restrict__ out) {
  __shared__ float sA[2][16384];   // 2 x 64 KB A stage
  __shared__ float sR[4096];       // 16 KB partial-reduce
  const int tid = threadIdx.x;
  const int lane = tid & 63;
  const int w = tid >> 6;          // 0..7: wave's K-eighth
  const int row0 = blockIdx.x * 128;
  const float* eb = enc + (size_t)row0 * 1024;

  // ---- one-time B fragment load: 24 x 16B/lane, coalesced ----
  short8v bf[3][4][2];             // [split][ks][jt], static-indexed (unrolled)
#pragma unroll
  for (int ks = 0; ks < 4; ++ks)
#pragma unroll
    for (int jt = 0; jt < 2; ++jt)
#pragma unroll
      for (int sp = 0; sp < 3; ++sp) {
        const int ci = 2 * w + (ks >> 1);
        const int q = (ks & 1) * 2 + jt;
        bf[sp][ks][jt] = *(const short8v*)(WB + sp * 32768 + ci * 2048 + q * 512 + lane * 8);
      }

  // stage rg (16 rows x 4 KB, contiguous 64 KB): wave w stages rows 2w,2w+1
  // (4 quarter-row instrs each). Source slot pre-swizzled ^(row&7).
  auto stageA = [&](int rg, int buf) {
#pragma unroll
    for (int i = 0; i < 8; ++i) {
      const int u = w * 8 + i;
      const int row = u >> 2, q = u & 3;
      gload_lds16(eb + (size_t)(rg * 16 + row) * 1024 + q * 256 + (lane ^ (row & 7)) * 4,
                  &sA[buf][row * 1024 + q * 256]);
    }
  };

  stageA(0, 0);
  stageA(1, 1);

#pragma unroll
  for (int rg = 0; rg < 8; ++rg) {
    if (rg < 7) asm volatile("s_waitcnt vmcnt(8)" ::: "memory");  // rg's loads done; rg+1 in flight
    else        asm volatile("s_waitcnt vmcnt(0)" ::: "memory");
    __builtin_amdgcn_s_barrier();
    asm volatile("" ::: "memory");
    __builtin_amdgcn_sched_barrier(0);

    // ---- compute rg: partial over wave's K-eighth ----
    float4v a0 = {0.0f, 0.0f, 0.0f, 0.0f};
    float4v a1c = {0.0f, 0.0f, 0.0f, 0.0f};
    {
      const int r = lane & 15;
      const int g = lane >> 4;
      const int rx7 = r & 7;
      const float* base = &sA[rg & 1][r * 1024];
#pragma unroll
      for (int ks = 0; ks < 4; ++ks) {
        const int v = w * 32 + ks * 8 + g * 2;        // float4 slot in row
        const int q = v >> 6;
        const int s = v & 63;
        const float4 e0 = *(const float4*)&base[q * 256 + ((s ^ rx7) << 2)];
        const float4 e1 = *(const float4*)&base[q * 256 + (((s + 1) ^ rx7) << 2)];
        S8 f1a, f2a, f3a;
        const float vals[8] = {e0.x, e0.y, e0.z, e0.w, e1.x, e1.y, e1.z, e1.w};
#pragma unroll
        for (int t = 0; t < 8; ++t) {
          const float vv = vals[t];
          const uint b = __float_as_uint(vv);
          f1a.u[t] = (ushort)(b >> 16);
          const float p1 = __uint_as_float(b & 0xFFFF0000u);
          const float r1 = vv - p1;
          const uint b2 = __float_as_uint(r1);
          f2a.u[t] = (ushort)(b2 >> 16);
          const float p2 = __uint_as_float(b2 & 0xFFFF0000u);
          const float r2 = r1 - p2;
          f3a.u[t] = (ushort)(__float_as_uint(r2) >> 16);
        }
#pragma unroll
        for (int jt = 0; jt < 2; ++jt) {
          float4v acc = jt ? a1c : a0;
          acc = __builtin_amdgcn_mfma_f32_16x16x32_bf16(f1a.v, bf[0][ks][jt], acc, 0, 0, 0);
          acc = __builtin_amdgcn_mfma_f32_16x16x32_bf16(f2a.v, bf[0][ks][jt], acc, 0, 0, 0);
          acc = __builtin_amdgcn_mfma_f32_16x16x32_bf16(f1a.v, bf[1][ks][jt], acc, 0, 0, 0);
          acc = __builtin_amdgcn_mfma_f32_16x16x32_bf16(f2a.v, bf[1][ks][jt], acc, 0, 0, 0);
          acc = __builtin_amdgcn_mfma_f32_16x16x32_bf16(f3a.v, bf[0][ks][jt], acc, 0, 0, 0);
          acc = __builtin_amdgcn_mfma_f32_16x16x32_bf16(f1a.v, bf[2][ks][jt], acc, 0, 0, 0);
          if (jt) a1c = acc; else a0 = acc;
        }
      }
    }

    // ---- write partials, barrier, then prefetch rg+2 + reduce/store ----
    {
      float* pw = &sR[(w * 64 + lane) * 8];
      *(float4v*)&pw[0] = a0;
      *(float4v*)&pw[4] = a1c;
    }
    asm volatile("" ::: "memory");
    __builtin_amdgcn_s_barrier();             // compute+partials done: buf reusable
    asm volatile("" ::: "memory");
    if (rg + 2 < 8) stageA(rg + 2, rg & 1);   // in flight across reduce + next compute

    if (tid < 384) {                          // 16 rows x 24 cols
      const int rr = tid & 15, j = tid >> 4;
      const int lane_src = (j < 16 ? j : j - 16) + ((rr >> 2) << 4);
      const int fi = (j < 16 ? 0 : 4) + (rr & 3);
      float ssum = bias[j];
#pragma unroll
      for (int ww = 0; ww < 8; ++ww) ssum += sR[(ww * 64 + lane_src) * 8 + fi];
      out[1 + (size_t)(j >> 3) * (BT * 8) + (size_t)(row0 + rg * 16 + rr) * 8 + (j & 7)] = ssum;
    }
  }
}

// ---------- CRF v6: chunk-parallel scan (unchanged) --------------------------
__global__ __launch_bounds__(512) void crf_kernel(const int* __restrict__ labels,
                                                  const float* __restrict__ startT,
                                                  const float* __restrict__ endT,
                                                  const float* __restrict__ trans,
                                                  float* __restrict__ d_out) {
  __shared__ float sA[32 * 64];          // chunk matrices [i][p][c]
  __shared__ float sVB[32 * 8];          // vit boundary vectors
  __shared__ int   sBP[512];             // vit packed bp words
  __shared__ int   sMap[32 * 8];         // vit exit->entry maps
  __shared__ int   sEnt[32];             // vit chunk entry states
  __shared__ float sRed[32];             // fwd numerator partials
  __shared__ unsigned char sTags[512];
  __shared__ int sTerm;

  const int tid = threadIdx.x;
  const int lane = tid & 63;
  const int w = tid >> 6;
  const int c = lane & 7;
  const int p = (lane >> 3) & 7;
  const int role = (blockIdx.x >= 192);
  const int seq = role ? blockIdx.x - 192 : blockIdx.x;
  const int k = seq >> 6, b = seq & 63;
  const float* em = d_out + 1 + ((size_t)k * BT + (size_t)b * 512) * 8;
  const float* trk = trans + k * 64;
  const int* lab = labels + b * (NK * NT) + k * NT;

  float Txc[8];
#pragma unroll
  for (int kk = 0; kk < 8; ++kk) Txc[kk] = trk[(c ^ kk) * 8 + c];
  const float Tpc = trk[p * 8 + c];
  const float startc = startT[k * 8 + c];
  const float endc = endT[k * 8 + c];

  if (!role) {
    // ========================= FORWARD (logZ + loss) ========================
    float Mxc[8];
#pragma unroll
    for (int kk = 0; kk < 8; ++kk) Mxc[kk] = __expf(Txc[kk]);

    // phase 1: linear-domain chunk matrices, constant 2^-32 renorm at step 8
#pragma unroll 1
    for (int it = 0; it < 4; ++it) {
      const int i = w * 4 + it;
      const int t0 = i * 16;
      const int te = (t0 + 16 < 512) ? (t0 + 16) : 511;
      float EX[16];
      EX[0] = em[(t0 + 1) * 8 + c];             // raw em for init
#pragma unroll
      for (int j = 1; j < 16; ++j) {
        int t = t0 + 1 + j;
        EX[j] = (t <= te) ? __expf(em[t * 8 + c]) : 1.0f;
      }
      float V = __expf(Tpc + EX[0]);
#pragma unroll
      for (int j = 1; j < 16; ++j) {
        int t = t0 + 1 + j;
        if (t <= te) {
          float x1 = dppf<QP1>(V), x2 = dppf<QP2>(V), x3 = dppf<QP2>(x1);
          float x7 = dppf<HM>(V), x6 = dppf<QP1>(x7), x5 = dppf<QP2>(x7), x4 = dppf<QP2>(x6);
          float s01 = fmaf(x1, Mxc[1], V * Mxc[0]);
          float s23 = fmaf(x3, Mxc[3], x2 * Mxc[2]);
          float s45 = fmaf(x5, Mxc[5], x4 * Mxc[4]);
          float s67 = fmaf(x7, Mxc[7], x6 * Mxc[6]);
          V = ((s01 + s23) + (s45 + s67)) * EX[j];
        }
        if (j == 8) V *= 0x1p-32f;              // exact pow2 renorm (uniform)
      }
      sA[i * 64 + lane] = V;
    }
    __syncthreads();

    float logZ = 0.0f;
    if (w == 0) {
      // phase 2: 32-step alpha scan
      float al = __expf(startc + em[c]);
      float lz = 0.0f;
#pragma unroll 1
      for (int i = 0; i < 32; ++i) {
        const float* Ai = &sA[i * 64];
        float A0 = Ai[(c ^ 0) * 8 + c], A1 = Ai[(c ^ 1) * 8 + c];
        float A2 = Ai[(c ^ 2) * 8 + c], A3 = Ai[(c ^ 3) * 8 + c];
        float A4 = Ai[(c ^ 4) * 8 + c], A5 = Ai[(c ^ 5) * 8 + c];
        float A6 = Ai[(c ^ 6) * 8 + c], A7 = Ai[(c ^ 7) * 8 + c];
        float a1 = dppf<QP1>(al), a2 = dppf<QP2>(al), a3 = dppf<QP2>(a1);
        float a4 = dppf<ROR4>(al), a5 = dppf<ROR4>(a1), a6 = dppf<ROR4>(a2), a7 = dppf<ROR4>(a3);
        float s01 = fmaf(a1, A1, al * A0);
        float s23 = fmaf(a3, A3, a2 * A2);
        float s45 = fmaf(a5, A5, a4 * A4);
        float s67 = fmaf(a7, A7, a6 * A6);
        float s = (s01 + s23) + (s45 + s67);
        float ss = s;
        ss += dppf<QP1>(ss); ss += dppf<QP2>(ss); ss += dppf<ROR4>(ss);
        lz += __logf(ss);
        al = s * (1.0f / ss);
      }
      float se = al * __expf(endc);
      se += dppf<QP1>(se); se += dppf<QP2>(se); se += dppf<ROR4>(se);
      logZ = lz + __logf(se) + 1024.0f * 0.69314718055994531f;  // 32 chunks x 32 ln2
    } else {
      // phase 2 (waves 1-7): gold-path numerator
      int idx = (w - 1) * 64 + lane;            // 0..447
      float ns = 0.0f;
      {
        int tg = lab[idx];
        ns += em[(size_t)idx * 8 + tg] + trk[tg * 8 + lab[idx + 1]];
      }
      if (idx < 64) {
        int t = idx + 448;
        int tg = lab[t];
        ns += em[(size_t)t * 8 + tg];
        if (t < 511) ns += trk[tg * 8 + lab[t + 1]];
      }
      ns += dppf<QP1>(ns); ns += dppf<QP2>(ns); ns += dppf<HM>(ns); ns += dppf<ROR8>(ns);
      if ((lane & 15) == 0) sRed[(w - 1) * 4 + (lane >> 4)] = ns;
    }
    __syncthreads();
    if (tid == 0) {
      float num = startT[k * 8 + lab[0]] + endT[k * 8 + lab[511]];
#pragma unroll
      for (int u = 0; u < 28; ++u) num += sRed[u];
      atomicAdd(d_out, logZ - num);
    }
  } else {
    // ========================= VITERBI (preds) ==============================
    // phase 1: max-plus chunk matrices
#pragma unroll 1
    for (int it = 0; it < 4; ++it) {
      const int i = w * 4 + it;
      const int t0 = i * 16;
      const int te = (t0 + 16 < 512) ? (t0 + 16) : 511;
      float emv[16];
#pragma unroll
      for (int j = 0; j < 16; ++j) {
        int t = t0 + 1 + j;
        emv[j] = (t <= te) ? em[t * 8 + c] : 0.0f;
      }
      float V = Tpc + emv[0];
#pragma unroll
      for (int j = 1; j < 16; ++j) {
        int t = t0 + 1 + j;
        if (t <= te) {
          float x1 = dppf<QP1>(V), x2 = dppf<QP2>(V), x3 = dppf<QP2>(x1);
          float x7 = dppf<HM>(V), x6 = dppf<QP1>(x7), x5 = dppf<QP2>(x7), x4 = dppf<QP2>(x6);
          float c0 = V + Txc[0], c1 = x1 + Txc[1], c2 = x2 + Txc[2], c3 = x3 + Txc[3];
          float c4 = x4 + Txc[4], c5 = x5 + Txc[5], c6 = x6 + Txc[6], c7 = x7 + Txc[7];
          float m0 = fmaxf(fmaxf(c0, c1), c2);
          float m1 = fmaxf(fmaxf(c3, c4), c5);
          float m2 = fmaxf(c6, c7);
          V = fmaxf(fmaxf(m0, m1), m2) + emv[j];
        }
      }
      sA[i * 64 + lane] = V;
    }
    __syncthreads();

    // phase 2: v scan (wave 0), store boundary vectors
    if (w == 0) {
      float v = startc + em[c];
#pragma unroll 1
      for (int i = 0; i < 32; ++i) {
        if (lane < 8) sVB[i * 8 + c] = v;
        const float* Ai = &sA[i * 64];
        float A0 = Ai[(c ^ 0) * 8 + c], A1 = Ai[(c ^ 1) * 8 + c];
        float A2 = Ai[(c ^ 2) * 8 + c], A3 = Ai[(c ^ 3) * 8 + c];
        float A4 = Ai[(c ^ 4) * 8 + c], A5 = Ai[(c ^ 5) * 8 + c];
        float A6 = Ai[(c ^ 6) * 8 + c], A7 = Ai[(c ^ 7) * 8 + c];
        float a1 = dppf<QP1>(v), a2 = dppf<QP2>(v), a3 = dppf<QP2>(a1);
        float a4 = dppf<ROR4>(v), a5 = dppf<ROR4>(a1), a6 = dppf<ROR4>(a2), a7 = dppf<ROR4>(a3);
        float c0 = v + A0, c1 = a1 + A1, c2 = a2 + A2, c3 = a3 + A3;
        float c4 = a4 + A4, c5 = a5 + A5, c6 = a6 + A6, c7 = a7 + A7;
        float m0 = fmaxf(fmaxf(c0, c1), c2);
        float m1 = fmaxf(fmaxf(c3, c4), c5);
        float m2 = fmaxf(c6, c7);
        v = fmaxf(fmaxf(m0, m1), m2);
      }
      float lv = v + endc;
      int li = c;
      {
        float ov; int oi; bool take;
        ov = dppf<QP1>(lv); oi = dppi<QP1>(li);
        take = (ov > lv) || (ov == lv && oi < li); lv = take ? ov : lv; li = take ? oi : li;
        ov = dppf<QP2>(lv); oi = dppi<QP2>(li);
        take = (ov > lv) || (ov == lv && oi < li); lv = take ? ov : lv; li = take ? oi : li;
        ov = dppf<ROR4>(lv); oi = dppi<ROR4>(li);
        take = (ov > lv) || (ov == lv && oi < li); lv = take ? ov : lv; li = take ? oi : li;
      }
      if (lane == 0) sTerm = li;
    }
    __syncthreads();

    // phase 3: exact bp recompute, 8 chunk-slots per wave (waves 0-3)
    if (w < 4) {
      const int u = lane >> 3;
      const int i = w * 8 + u;
      const int t0 = i * 16;
      const int te = (t0 + 16 < 512) ? (t0 + 16) : 511;
      float emv[16];
#pragma unroll
      for (int j = 0; j < 16; ++j) {
        int t = t0 + 1 + j;
        emv[j] = (t <= te) ? em[t * 8 + c] : 0.0f;
      }
      float v = sVB[i * 8 + c];
#pragma unroll
      for (int j = 0; j < 16; ++j) {
        int t = t0 + 1 + j;
        if (t <= te) {
          float x1 = dppf<QP1>(v), x2 = dppf<QP2>(v), x3 = dppf<QP2>(x1);
          float x7 = dppf<HM>(v), x6 = dppf<QP1>(x7), x5 = dppf<QP2>(x7), x4 = dppf<QP2>(x6);
          float c0 = v + Txc[0], c1 = x1 + Txc[1], c2 = x2 + Txc[2], c3 = x3 + Txc[3];
          float c4 = x4 + Txc[4], c5 = x5 + Txc[5], c6 = x6 + Txc[6], c7 = x7 + Txc[7];
          float m0 = fmaxf(fmaxf(c0, c1), c2);
          float m1 = fmaxf(fmaxf(c3, c4), c5);
          float m2 = fmaxf(c6, c7);
          float best = fmaxf(fmaxf(m0, m1), m2);
          int a0 = (c0 == best) ? (c ^ 0) : 8;
          int a1i = (c1 == best) ? (c ^ 1) : 8;
          int a2i = (c2 == best) ? (c ^ 2) : 8;
          int a3i = (c3 == best) ? (c ^ 3) : 8;
          int a4i = (c4 == best) ? (c ^ 4) : 8;
          int a5i = (c5 == best) ? (c ^ 5) : 8;
          int a6i = (c6 == best) ? (c ^ 6) : 8;
          int a7i = (c7 == best) ? (c ^ 7) : 8;
          int arg = min(min(min(a0, a1i), min(a2i, a3i)),
                        min(min(a4i, a5i), min(a6i, a7i)));
          v = best + emv[j];
          int wd = arg << (3 * c);
          wd |= dppi<QP1>(wd); wd |= dppi<QP2>(wd); wd |= dppi<HM>(wd);
          if ((lane & 7) == 0) sBP[t] = wd;
        }
      }
    }
    __syncthreads();

    // phase 4a: per-chunk exit->entry maps (all 8 exit states in parallel)
    if (w < 4) {
      const int u = lane >> 3;
      const int i = w * 8 + u;
      const int t0 = i * 16;
      const int te = (t0 + 16 < 512) ? (t0 + 16) : 511;
      int tag = c;
#pragma unroll
      for (int j = 16; j >= 1; --j) {
        int t = t0 + j;
        if (t <= te) tag = (sBP[t] >> (3 * tag)) & 7;
      }
      sMap[i * 8 + c] = tag;
    }
    __syncthreads();
    // phase 4b: compose maps -> chunk entry states
    if (tid == 0) {
      int cur = sTerm;
#pragma unroll 1
      for (int i = 31; i >= 0; --i) { cur = sMap[i * 8 + cur]; sEnt[i] = cur; }
    }
    __syncthreads();
    // phase 4c: emit tags per chunk (32 parallel lanes)
    if (w == 0 && lane < 32) {
      const int i = lane;
      const int t0 = i * 16;
      const int te = (t0 + 16 < 512) ? (t0 + 16) : 511;
      int tag = (i == 31) ? sTerm : sEnt[i + 1];
      if (i == 31) sTags[511] = (unsigned char)tag;
#pragma unroll
      for (int j = 16; j >= 1; --j) {
        int t = t0 + j;
        if (t <= te) { tag = (sBP[t] >> (3 * tag)) & 7; sTags[t - 1] = (unsigned char)tag; }
      }
    }
    __syncthreads();
    // phase 5: coalesced pred store
    float* outp = d_out + 1 + LOGITS_N + (size_t)seq * 512;
    outp[tid] = (float)sTags[tid];
  }
}

extern "C" void kernel_launch(void* const* d_in, const int* in_sizes, int n_in,
                              void* d_out, int out_size, void* d_ws, size_t ws_size,
                              hipStream_t stream) {
  const float* enc    = (const float*)d_in[0];
  const int*   labels = (const int*)  d_in[1];
  const float* W      = (const float*)d_in[2];
  const float* bias   = (const float*)d_in[3];
  const float* startT = (const float*)d_in[4];
  const float* endT   = (const float*)d_in[5];
  const float* trans  = (const float*)d_in[6];
  float* out = (float*)d_out;
  ushort* WB = (ushort*)d_ws;   // 3 x 64 KB frag-ready split weights

  init_kernel<<<dim3(128), dim3(256), 0, stream>>>(W, WB, out);
  proj_kernel<<<dim3(256), dim3(512), 0, stream>>>(enc, WB, bias, out);
  crf_kernel<<<dim3(384), dim3(512), 0, stream>>>(labels, startT, endT, trans, out);
}

// Round 9
// 229.948 us; speedup vs baseline: 1.0071x; 1.0071x over previous
//
#include <hip/hip_runtime.h>

#define NB 64
#define NT 512
#define NH 1024
#define NC 8
#define NK 3
#define BT (NB*NT)             // 32768
#define LOGITS_N (NK*BT*NC)    // 786432

typedef unsigned short ushort;
typedef unsigned int uint;
typedef __attribute__((ext_vector_type(8))) short short8v;
typedef __attribute__((ext_vector_type(4))) float float4v;
union S8 { short8v v; ushort u[8]; };

// DPP controls
#define QP1  0xB1   // quad_perm [1,0,3,2] -> lane^1
#define QP2  0x4E   // quad_perm [2,3,0,1] -> lane^2
#define ROR4 0x124  // row_ror:4  -> lane^4 (value must be 8-group replicated)
#define ROR8 0x128  // row_ror:8  -> exact lane^8 within 16-row
#define HM   0x141  // row_half_mirror -> exact lane^7 within 8

template<int CTRL>
__device__ __forceinline__ float dppf(float x) {
  return __int_as_float(__builtin_amdgcn_update_dpp(0, __float_as_int(x), CTRL, 0xF, 0xF, true));
}
template<int CTRL>
__device__ __forceinline__ int dppi(int x) {
  return __builtin_amdgcn_update_dpp(0, x, CTRL, 0xF, 0xF, true);
}

__device__ __forceinline__ void gload_lds16(const void* g, void* l) {
  __builtin_amdgcn_global_load_lds(
      (const __attribute__((address_space(1))) void*)g,
      (__attribute__((address_space(3))) void*)l, 16, 0, 0);
}

// ---------- init: W -> frag-ready 3-way bf16 split WB[3][16ci][4q][64l][8] --
__global__ __launch_bounds__(256) void init_kernel(const float* __restrict__ W,
                                                   ushort* __restrict__ WB,
                                                   float* __restrict__ out) {
  const int i = blockIdx.x * 256 + threadIdx.x;   // 0..32767
  const int ci = i >> 11;
  const int rem = i & 2047;
  const int q = rem >> 9;
  const int l = (rem >> 3) & 63;
  const int e = i & 7;
  const int k = ci * 64 + (q >> 1) * 32 + ((l >> 4) << 3) + e;
  const int j = (q & 1) * 16 + (l & 15);
  float v = 0.0f;
  if (j < 24) v = W[(j >> 3) * (NC * NH) + (j & 7) * NH + k];
  const uint b = __float_as_uint(v);
  const ushort h1 = (ushort)(b >> 16);
  const float f1 = __uint_as_float(b & 0xFFFF0000u);
  const float r1 = v - f1;
  const uint b2 = __float_as_uint(r1);
  const ushort h2 = (ushort)(b2 >> 16);
  const float f2 = __uint_as_float(b2 & 0xFFFF0000u);
  const float r2 = r1 - f2;
  const ushort h3 = (ushort)(__float_as_uint(r2) >> 16);
  WB[i] = h1;
  WB[32768 + i] = h2;
  WB[65536 + i] = h3;
  if (i == 0) out[0] = 0.0f;
}

// ---------- proj v16: v13 pipeline at 4 barrier groups / CU -----------------
// 1024 blocks x 128 thr (2 waves). Block = 32 rows x full K=1024; 16 chunks
// of K=64 visited in order t^(blockIdx&15). LDS = sA 2x8KB + sB 2x12KB =
// 40 KB exactly -> 4 blocks/CU (8 waves/CU). Rationale: per-CU BW fair share
// is only ~25 GB/s; the loop's stage->compute->sync(vmcnt-drain) leaves the
// memory pipe idle ~half of each group's cycle, and proj time has tracked
// blocks/CU (1->~68us, 2->~57us) across v12-v15 while pattern/pipeline
// changes were neutral. 4 independent groups interleave the drain windows.
// Compute per wave is byte-identical to v13 (wave w owns rows w*16..+15 x all
// 24 cols; MFMA 16x16x32 bf16, 3+3 Dekker split; C/D col=lane&15,
// row=(lane>>4)*4+reg). m97 one-__syncthreads-per-chunk pattern.
__global__ __launch_bounds__(128, 2) void proj_kernel(const float* __restrict__ enc,
                                                      const ushort* __restrict__ WB,
                                                      const float* __restrict__ bias,
                                                      float* __restrict__ out) {
  __shared__ float  sA[2][2048];    // 16 KB (32 rows x 64 k per buf)
  __shared__ ushort sB[2][6144];    // 24 KB
  const int tid = threadIdx.x;
  const int lane = tid & 63;
  const int w = tid >> 6;           // 0..1
  const int row0 = blockIdx.x * 32;
  const int chrot = blockIdx.x & 15;
  const float* eb = enc + (size_t)row0 * 1024;

  float4v acc0 = {0.0f, 0.0f, 0.0f, 0.0f};
  float4v acc1 = {0.0f, 0.0f, 0.0f, 0.0f};

  // stage A chunk cx: 4 instrs/wave, each 1KB = 4 rows x 256B; source slot
  // pre-swizzled ^(r&15) so the frag-load ds_read_b128 is bank-schedulable.
  auto stageA = [&](int cx, int buf) {
#pragma unroll
    for (int i = 0; i < 4; ++i) {
      const int rbase = w * 16 + i * 4;
      const int r = rbase + (lane >> 4);
      const int s = (lane & 15) ^ (r & 15);
      gload_lds16(eb + (size_t)r * 1024 + cx * 64 + s * 4, &sA[buf][rbase * 64]);
    }
  };
  // stage B chunk cx: 6 instrs/wave (u = i*2+w covers [sp][q] = u>>2,u&3),
  // lane-linear frag-ready layout (no swizzle needed).
  auto stageB = [&](int cx, int buf) {
#pragma unroll
    for (int i = 0; i < 6; ++i) {
      const int u = i * 2 + w;       // 0..11
      const int sp = u >> 2, q = u & 3;
      gload_lds16(WB + sp * 32768 + cx * 2048 + q * 512 + lane * 8,
                  &sB[buf][u * 512]);
    }
  };

  auto compute = [&](int buf) {
    const float* ar = &sA[buf][(w * 16 + (lane & 15)) * 64];
    const ushort* sBf = &sB[buf][0];
    const int rx = lane & 15;
    const int g = lane >> 4;
#pragma unroll
    for (int kkb = 0; kkb < 2; ++kkb) {
      const int s0 = kkb * 8 + g * 2;
      const float4 e0 = *(const float4*)&ar[(s0 ^ rx) * 4];
      const float4 e1 = *(const float4*)&ar[((s0 + 1) ^ rx) * 4];
      S8 a1, a2, a3;
      const float vals[8] = {e0.x, e0.y, e0.z, e0.w, e1.x, e1.y, e1.z, e1.w};
#pragma unroll
      for (int t = 0; t < 8; ++t) {
        const float v = vals[t];
        const uint b = __float_as_uint(v);
        a1.u[t] = (ushort)(b >> 16);
        const float f1 = __uint_as_float(b & 0xFFFF0000u);
        const float r1 = v - f1;
        const uint b2 = __float_as_uint(r1);
        a2.u[t] = (ushort)(b2 >> 16);
        const float f2 = __uint_as_float(b2 & 0xFFFF0000u);
        const float r2 = r1 - f2;
        a3.u[t] = (ushort)(__float_as_uint(r2) >> 16);
      }
#pragma unroll
      for (int jt = 0; jt < 2; ++jt) {
        const int q = kkb * 2 + jt;
        const short8v w1 = *(const short8v*)&sBf[0 * 2048 + q * 512 + lane * 8];
        const short8v w2 = *(const short8v*)&sBf[1 * 2048 + q * 512 + lane * 8];
        const short8v w3 = *(const short8v*)&sBf[2 * 2048 + q * 512 + lane * 8];
        float4v acc = jt ? acc1 : acc0;
        acc = __builtin_amdgcn_mfma_f32_16x16x32_bf16(a1.v, w1, acc, 0, 0, 0);
        acc = __builtin_amdgcn_mfma_f32_16x16x32_bf16(a2.v, w1, acc, 0, 0, 0);
        acc = __builtin_amdgcn_mfma_f32_16x16x32_bf16(a1.v, w2, acc, 0, 0, 0);
        acc = __builtin_amdgcn_mfma_f32_16x16x32_bf16(a2.v, w2, acc, 0, 0, 0);
        acc = __builtin_amdgcn_mfma_f32_16x16x32_bf16(a3.v, w1, acc, 0, 0, 0);
        acc = __builtin_amdgcn_mfma_f32_16x16x32_bf16(a1.v, w3, acc, 0, 0, 0);
        if (jt) acc1 = acc; else acc0 = acc;
      }
    }
  };

  stageA(chrot, 0);                 // t=0 -> cx = 0 ^ chrot
  stageB(chrot, 0);
  __syncthreads();                  // chunk 0 resident

#pragma unroll 1
  for (int t = 0; t < 16; ++t) {
    const int buf = t & 1;
    if (t < 15) {
      const int cx = (t + 1) ^ chrot;
      stageA(cx, buf ^ 1);
      stageB(cx, buf ^ 1);
    }
    compute(buf);
    __syncthreads();                // drains prefetch; buf free next iter
  }

  // epilogue: direct stores from MFMA C/D layout (+bias); no LDS reduce.
  const int g = lane >> 4, cx2 = lane & 15;
#pragma unroll
  for (int jt = 0; jt < 2; ++jt) {
    const int j = jt * 16 + cx2;
    if (j < 24) {
      const float bj = bias[j];
      const float4v acc = jt ? acc1 : acc0;
      float* ob = out + 1 + (size_t)(j >> 3) * (BT * 8) + (j & 7);
#pragma unroll
      for (int qq = 0; qq < 4; ++qq) {
        const int grow = row0 + w * 16 + g * 4 + qq;
        ob[(size_t)grow * 8] = acc[qq] + bj;
      }
    }
  }
}

// ---------- CRF v6: chunk-parallel scan (unchanged) --------------------------
__global__ __launch_bounds__(512) void crf_kernel(const int* __restrict__ labels,
                                                  const float* __restrict__ startT,
                                                  const float* __restrict__ endT,
                                                  const float* __restrict__ trans,
                                                  float* __restrict__ d_out) {
  __shared__ float sA[32 * 64];          // chunk matrices [i][p][c]
  __shared__ float sVB[32 * 8];          // vit boundary vectors
  __shared__ int   sBP[512];             // vit packed bp words
  __shared__ int   sMap[32 * 8];         // vit exit->entry maps
  __shared__ int   sEnt[32];             // vit chunk entry states
  __shared__ float sRed[32];             // fwd numerator partials
  __shared__ unsigned char sTags[512];
  __shared__ int sTerm;

  const int tid = threadIdx.x;
  const int lane = tid & 63;
  const int w = tid >> 6;
  const int c = lane & 7;
  const int p = (lane >> 3) & 7;
  const int role = (blockIdx.x >= 192);
  const int seq = role ? blockIdx.x - 192 : blockIdx.x;
  const int k = seq >> 6, b = seq & 63;
  const float* em = d_out + 1 + ((size_t)k * BT + (size_t)b * 512) * 8;
  const float* trk = trans + k * 64;
  const int* lab = labels + b * (NK * NT) + k * NT;

  float Txc[8];
#pragma unroll
  for (int kk = 0; kk < 8; ++kk) Txc[kk] = trk[(c ^ kk) * 8 + c];
  const float Tpc = trk[p * 8 + c];
  const float startc = startT[k * 8 + c];
  const float endc = endT[k * 8 + c];

  if (!role) {
    // ========================= FORWARD (logZ + loss) ========================
    float Mxc[8];
#pragma unroll
    for (int kk = 0; kk < 8; ++kk) Mxc[kk] = __expf(Txc[kk]);

    // phase 1: linear-domain chunk matrices, constant 2^-32 renorm at step 8
#pragma unroll 1
    for (int it = 0; it < 4; ++it) {
      const int i = w * 4 + it;
      const int t0 = i * 16;
      const int te = (t0 + 16 < 512) ? (t0 + 16) : 511;
      float EX[16];
      EX[0] = em[(t0 + 1) * 8 + c];             // raw em for init
#pragma unroll
      for (int j = 1; j < 16; ++j) {
        int t = t0 + 1 + j;
        EX[j] = (t <= te) ? __expf(em[t * 8 + c]) : 1.0f;
      }
      float V = __expf(Tpc + EX[0]);
#pragma unroll
      for (int j = 1; j < 16; ++j) {
        int t = t0 + 1 + j;
        if (t <= te) {
          float x1 = dppf<QP1>(V), x2 = dppf<QP2>(V), x3 = dppf<QP2>(x1);
          float x7 = dppf<HM>(V), x6 = dppf<QP1>(x7), x5 = dppf<QP2>(x7), x4 = dppf<QP2>(x6);
          float s01 = fmaf(x1, Mxc[1], V * Mxc[0]);
          float s23 = fmaf(x3, Mxc[3], x2 * Mxc[2]);
          float s45 = fmaf(x5, Mxc[5], x4 * Mxc[4]);
          float s67 = fmaf(x7, Mxc[7], x6 * Mxc[6]);
          V = ((s01 + s23) + (s45 + s67)) * EX[j];
        }
        if (j == 8) V *= 0x1p-32f;              // exact pow2 renorm (uniform)
      }
      sA[i * 64 + lane] = V;
    }
    __syncthreads();

    float logZ = 0.0f;
    if (w == 0) {
      // phase 2: 32-step alpha scan
      float al = __expf(startc + em[c]);
      float lz = 0.0f;
#pragma unroll 1
      for (int i = 0; i < 32; ++i) {
        const float* Ai = &sA[i * 64];
        float A0 = Ai[(c ^ 0) * 8 + c], A1 = Ai[(c ^ 1) * 8 + c];
        float A2 = Ai[(c ^ 2) * 8 + c], A3 = Ai[(c ^ 3) * 8 + c];
        float A4 = Ai[(c ^ 4) * 8 + c], A5 = Ai[(c ^ 5) * 8 + c];
        float A6 = Ai[(c ^ 6) * 8 + c], A7 = Ai[(c ^ 7) * 8 + c];
        float a1 = dppf<QP1>(al), a2 = dppf<QP2>(al), a3 = dppf<QP2>(a1);
        float a4 = dppf<ROR4>(al), a5 = dppf<ROR4>(a1), a6 = dppf<ROR4>(a2), a7 = dppf<ROR4>(a3);
        float s01 = fmaf(a1, A1, al * A0);
        float s23 = fmaf(a3, A3, a2 * A2);
        float s45 = fmaf(a5, A5, a4 * A4);
        float s67 = fmaf(a7, A7, a6 * A6);
        float s = (s01 + s23) + (s45 + s67);
        float ss = s;
        ss += dppf<QP1>(ss); ss += dppf<QP2>(ss); ss += dppf<ROR4>(ss);
        lz += __logf(ss);
        al = s * (1.0f / ss);
      }
      float se = al * __expf(endc);
      se += dppf<QP1>(se); se += dppf<QP2>(se); se += dppf<ROR4>(se);
      logZ = lz + __logf(se) + 1024.0f * 0.69314718055994531f;  // 32 chunks x 32 ln2
    } else {
      // phase 2 (waves 1-7): gold-path numerator
      int idx = (w - 1) * 64 + lane;            // 0..447
      float ns = 0.0f;
      {
        int tg = lab[idx];
        ns += em[(size_t)idx * 8 + tg] + trk[tg * 8 + lab[idx + 1]];
      }
      if (idx < 64) {
        int t = idx + 448;
        int tg = lab[t];
        ns += em[(size_t)t * 8 + tg];
        if (t < 511) ns += trk[tg * 8 + lab[t + 1]];
      }
      ns += dppf<QP1>(ns); ns += dppf<QP2>(ns); ns += dppf<HM>(ns); ns += dppf<ROR8>(ns);
      if ((lane & 15) == 0) sRed[(w - 1) * 4 + (lane >> 4)] = ns;
    }
    __syncthreads();
    if (tid == 0) {
      float num = startT[k * 8 + lab[0]] + endT[k * 8 + lab[511]];
#pragma unroll
      for (int u = 0; u < 28; ++u) num += sRed[u];
      atomicAdd(d_out, logZ - num);
    }
  } else {
    // ========================= VITERBI (preds) ==============================
    // phase 1: max-plus chunk matrices
#pragma unroll 1
    for (int it = 0; it < 4; ++it) {
      const int i = w * 4 + it;
      const int t0 = i * 16;
      const int te = (t0 + 16 < 512) ? (t0 + 16) : 511;
      float emv[16];
#pragma unroll
      for (int j = 0; j < 16; ++j) {
        int t = t0 + 1 + j;
        emv[j] = (t <= te) ? em[t * 8 + c] : 0.0f;
      }
      float V = Tpc + emv[0];
#pragma unroll
      for (int j = 1; j < 16; ++j) {
        int t = t0 + 1 + j;
        if (t <= te) {
          float x1 = dppf<QP1>(V), x2 = dppf<QP2>(V), x3 = dppf<QP2>(x1);
          float x7 = dppf<HM>(V), x6 = dppf<QP1>(x7), x5 = dppf<QP2>(x7), x4 = dppf<QP2>(x6);
          float c0 = V + Txc[0], c1 = x1 + Txc[1], c2 = x2 + Txc[2], c3 = x3 + Txc[3];
          float c4 = x4 + Txc[4], c5 = x5 + Txc[5], c6 = x6 + Txc[6], c7 = x7 + Txc[7];
          float m0 = fmaxf(fmaxf(c0, c1), c2);
          float m1 = fmaxf(fmaxf(c3, c4), c5);
          float m2 = fmaxf(c6, c7);
          V = fmaxf(fmaxf(m0, m1), m2) + emv[j];
        }
      }
      sA[i * 64 + lane] = V;
    }
    __syncthreads();

    // phase 2: v scan (wave 0), store boundary vectors
    if (w == 0) {
      float v = startc + em[c];
#pragma unroll 1
      for (int i = 0; i < 32; ++i) {
        if (lane < 8) sVB[i * 8 + c] = v;
        const float* Ai = &sA[i * 64];
        float A0 = Ai[(c ^ 0) * 8 + c], A1 = Ai[(c ^ 1) * 8 + c];
        float A2 = Ai[(c ^ 2) * 8 + c], A3 = Ai[(c ^ 3) * 8 + c];
        float A4 = Ai[(c ^ 4) * 8 + c], A5 = Ai[(c ^ 5) * 8 + c];
        float A6 = Ai[(c ^ 6) * 8 + c], A7 = Ai[(c ^ 7) * 8 + c];
        float a1 = dppf<QP1>(v), a2 = dppf<QP2>(v), a3 = dppf<QP2>(a1);
        float a4 = dppf<ROR4>(v), a5 = dppf<ROR4>(a1), a6 = dppf<ROR4>(a2), a7 = dppf<ROR4>(a3);
        float c0 = v + A0, c1 = a1 + A1, c2 = a2 + A2, c3 = a3 + A3;
        float c4 = a4 + A4, c5 = a5 + A5, c6 = a6 + A6, c7 = a7 + A7;
        float m0 = fmaxf(fmaxf(c0, c1), c2);
        float m1 = fmaxf(fmaxf(c3, c4), c5);
        float m2 = fmaxf(c6, c7);
        v = fmaxf(fmaxf(m0, m1), m2);
      }
      float lv = v + endc;
      int li = c;
      {
        float ov; int oi; bool take;
        ov = dppf<QP1>(lv); oi = dppi<QP1>(li);
        take = (ov > lv) || (ov == lv && oi < li); lv = take ? ov : lv; li = take ? oi : li;
        ov = dppf<QP2>(lv); oi = dppi<QP2>(li);
        take = (ov > lv) || (ov == lv && oi < li); lv = take ? ov : lv; li = take ? oi : li;
        ov = dppf<ROR4>(lv); oi = dppi<ROR4>(li);
        take = (ov > lv) || (ov == lv && oi < li); lv = take ? ov : lv; li = take ? oi : li;
      }
      if (lane == 0) sTerm = li;
    }
    __syncthreads();

    // phase 3: exact bp recompute, 8 chunk-slots per wave (waves 0-3)
    if (w < 4) {
      const int u = lane >> 3;
      const int i = w * 8 + u;
      const int t0 = i * 16;
      const int te = (t0 + 16 < 512) ? (t0 + 16) : 511;
      float emv[16];
#pragma unroll
      for (int j = 0; j < 16; ++j) {
        int t = t0 + 1 + j;
        emv[j] = (t <= te) ? em[t * 8 + c] : 0.0f;
      }
      float v = sVB[i * 8 + c];
#pragma unroll
      for (int j = 0; j < 16; ++j) {
        int t = t0 + 1 + j;
        if (t <= te) {
          float x1 = dppf<QP1>(v), x2 = dppf<QP2>(v), x3 = dppf<QP2>(x1);
          float x7 = dppf<HM>(v), x6 = dppf<QP1>(x7), x5 = dppf<QP2>(x7), x4 = dppf<QP2>(x6);
          float c0 = v + Txc[0], c1 = x1 + Txc[1], c2 = x2 + Txc[2], c3 = x3 + Txc[3];
          float c4 = x4 + Txc[4], c5 = x5 + Txc[5], c6 = x6 + Txc[6], c7 = x7 + Txc[7];
          float m0 = fmaxf(fmaxf(c0, c1), c2);
          float m1 = fmaxf(fmaxf(c3, c4), c5);
          float m2 = fmaxf(c6, c7);
          float best = fmaxf(fmaxf(m0, m1), m2);
          int a0 = (c0 == best) ? (c ^ 0) : 8;
          int a1i = (c1 == best) ? (c ^ 1) : 8;
          int a2i = (c2 == best) ? (c ^ 2) : 8;
          int a3i = (c3 == best) ? (c ^ 3) : 8;
          int a4i = (c4 == best) ? (c ^ 4) : 8;
          int a5i = (c5 == best) ? (c ^ 5) : 8;
          int a6i = (c6 == best) ? (c ^ 6) : 8;
          int a7i = (c7 == best) ? (c ^ 7) : 8;
          int arg = min(min(min(a0, a1i), min(a2i, a3i)),
                        min(min(a4i, a5i), min(a6i, a7i)));
          v = best + emv[j];
          int wd = arg << (3 * c);
          wd |= dppi<QP1>(wd); wd |= dppi<QP2>(wd); wd |= dppi<HM>(wd);
          if ((lane & 7) == 0) sBP[t] = wd;
        }
      }
    }
    __syncthreads();

    // phase 4a: per-chunk exit->entry maps (all 8 exit states in parallel)
    if (w < 4) {
      const int u = lane >> 3;
      const int i = w * 8 + u;
      const int t0 = i * 16;
      const int te = (t0 + 16 < 512) ? (t0 + 16) : 511;
      int tag = c;
#pragma unroll
      for (int j = 16; j >= 1; --j) {
        int t = t0 + j;
        if (t <= te) tag = (sBP[t] >> (3 * tag)) & 7;
      }
      sMap[i * 8 + c] = tag;
    }
    __syncthreads();
    // phase 4b: compose maps -> chunk entry states
    if (tid == 0) {
      int cur = sTerm;
#pragma unroll 1
      for (int i = 31; i >= 0; --i) { cur = sMap[i * 8 + cur]; sEnt[i] = cur; }
    }
    __syncthreads();
    // phase 4c: emit tags per chunk (32 parallel lanes)
    if (w == 0 && lane < 32) {
      const int i = lane;
      const int t0 = i * 16;
      const int te = (t0 + 16 < 512) ? (t0 + 16) : 511;
      int tag = (i == 31) ? sTerm : sEnt[i + 1];
      if (i == 31) sTags[511] = (unsigned char)tag;
#pragma unroll
      for (int j = 16; j >= 1; --j) {
        int t = t0 + j;
        if (t <= te) { tag = (sBP[t] >> (3 * tag)) & 7; sTags[t - 1] = (unsigned char)tag; }
      }
    }
    __syncthreads();
    // phase 5: coalesced pred store
    float* outp = d_out + 1 + LOGITS_N + (size_t)seq * 512;
    outp[tid] = (float)sTags[tid];
  }
}

extern "C" void kernel_launch(void* const* d_in, const int* in_sizes, int n_in,
                              void* d_out, int out_size, void* d_ws, size_t ws_size,
                              hipStream_t stream) {
  const float* enc    = (const float*)d_in[0];
  const int*   labels = (const int*)  d_in[1];
  const float* W      = (const float*)d_in[2];
  const float* bias   = (const float*)d_in[3];
  const float* startT = (const float*)d_in[4];
  const float* endT   = (const float*)d_in[5];
  const float* trans  = (const float*)d_in[6];
  float* out = (float*)d_out;
  ushort* WB = (ushort*)d_ws;   // 3 x 64 KB frag-ready split weights

  init_kernel<<<dim3(128), dim3(256), 0, stream>>>(W, WB, out);
  proj_kernel<<<dim3(1024), dim3(128), 0, stream>>>(enc, WB, bias, out);
  crf_kernel<<<dim3(384), dim3(512), 0, stream>>>(labels, startT, endT, trans, out);
}